// Round 1
// 462.403 us; speedup vs baseline: 1.0525x; 1.0525x over previous
//
#include <hip/hip_runtime.h>
#include <math.h>

// B=8, T=2048, D=768. out[b,i,:768] = masked softmax attn (denominator over ALL
// causal j; sit-mask zeroes numerator only; row gated by mask_i), out[b,i,768:] = x[b,i].
//
// v4: bf16 K/V precomputed in workspace in TWO layouts:
//   xbf: per-16-row-tile, w-chunk-major, row-major within chunk, 16B-group XOR
//        swizzle (serves QK^T B-frags and Q-frag loads)
//   xvt: per-tile blocked-transpose (exact VTb layout; serves PV B-frags)
// Main kernel stages both with global_load_lds; each wave stages exactly the
// chunk it reads -> no stage barriers, counted vmcnt(6). 2 barriers/tile.
// Pair-balanced Q-tile remap: co-resident blocks (c, 63-c) sum to 130 tiles.
constexpr int kT = 2048;
constexpr int kD = 768;
constexpr int kTileShorts = 16 * kD;       // 12288 shorts per 16-row tile
constexpr int kTilesPerBatch = kT / 16;    // 128

typedef __attribute__((ext_vector_type(8))) short short8;
typedef __attribute__((ext_vector_type(4))) float f32x4;
typedef __attribute__((ext_vector_type(16))) float f32x16;

#define FB(f) __builtin_bit_cast(unsigned, (f))
__device__ __forceinline__ unsigned pk_hi16(unsigned hi, unsigned lo) {
  return __builtin_amdgcn_perm(hi, lo, 0x07060302);  // bf16 truncation pack
}
__device__ __forceinline__ unsigned pk_lo16(unsigned hi, unsigned lo) {
  return __builtin_amdgcn_perm(hi, lo, 0x05040100);
}

// Workgroup barrier WITHOUT the vmcnt(0) drain __syncthreads() emits.
// lgkmcnt(0) makes this wave's LDS writes visible; global(_load_lds) ops stay
// in flight. gfx9 waitcnt encoding: vmcnt=63, expcnt=7, lgkmcnt=0 -> 0xC07F.
__device__ __forceinline__ void lds_barrier() {
  asm volatile("" ::: "memory");
  __builtin_amdgcn_s_waitcnt(0xC07F);
  __builtin_amdgcn_s_barrier();
  asm volatile("" ::: "memory");
}

// Direct global->LDS copy, 16B/lane. LDS dest = wave-uniform base + lane*16.
__device__ __forceinline__ void gload_lds16(const void* g, void* l) {
  __builtin_amdgcn_global_load_lds(
      (const __attribute__((address_space(1))) unsigned int*)g,
      (__attribute__((address_space(3))) unsigned int*)l, 16, 0, 0);
}

// ---------------------------------------------------------------------------
// Prep: x f32 -> bf16 workspace, both layouts. One block per (b, tile).
//   xbf tile layout (shorts): w*3072 + j*192 + ((g ^ (j&7))<<3) + (dp&7)
//     where d = 192w + dp, g = dp>>3; value = bf16(x[16t+j][d]).
//   xvt tile layout: identical to the verified VTb staging of the prior kernel.
// ---------------------------------------------------------------------------
__global__ __launch_bounds__(256) void prep_bf16(
    const float* __restrict__ x,
    unsigned short* __restrict__ xbf, unsigned short* __restrict__ xvt)
{
  const int tid = threadIdx.x;
  const int w = tid >> 6, l = tid & 63;
  const int l15 = l & 15, q4 = l >> 4;
  const int bt = (int)blockIdx.x;            // b*128 + t
  const float* xb = x + (size_t)bt * 16 * kD;
  unsigned short* ob = xbf + (size_t)bt * kTileShorts;
  unsigned short* ov = xvt + (size_t)bt * kTileShorts;

#pragma unroll
  for (int it = 0; it < 3; ++it) {
    const int dq = l15 + 16 * it + 48 * w;   // global d-quad index, [0,192)
    unsigned lo[4], hi[4];
#pragma unroll
    for (int jj = 0; jj < 4; ++jj) {
      const float4 f = *(const float4*)(xb + (size_t)(q4 + 4 * jj) * kD + 4 * dq);
      lo[jj] = pk_hi16(FB(f.y), FB(f.x));    // bf16 d+1 | d+0
      hi[jj] = pk_hi16(FB(f.w), FB(f.z));    // bf16 d+3 | d+2
    }
    // ---- xbf: chunked row-major + 16B-group XOR swizzle ----
    const int dp = 4 * (l15 + 16 * it);      // d' within w-chunk, [0,192)
    const int g = dp >> 3, e0 = dp & 7;      // e0 in {0,4}
#pragma unroll
    for (int jj = 0; jj < 4; ++jj) {
      const int j = q4 + 4 * jj;
      uint2 v; v.x = lo[jj]; v.y = hi[jj];
      *(uint2*)&ob[w * 3072 + j * 192 + ((g ^ (j & 7)) << 3) + e0] = v;
    }
    // ---- xvt: VTb blocked transpose (verbatim from prior LDS staging) ----
    const int jb = (4 * q4) ^ (8 * ((dq >> 2) & 1));
    const int base = dq * 64 + jb;
    uint2 v;
    v.x = pk_lo16(lo[1], lo[0]); v.y = pk_lo16(lo[3], lo[2]);
    *(uint2*)&ov[base + ((0 ^ (dq & 3)) << 4)] = v;
    v.x = pk_hi16(lo[1], lo[0]); v.y = pk_hi16(lo[3], lo[2]);
    *(uint2*)&ov[base + ((1 ^ (dq & 3)) << 4)] = v;
    v.x = pk_lo16(hi[1], hi[0]); v.y = pk_lo16(hi[3], hi[2]);
    *(uint2*)&ov[base + ((2 ^ (dq & 3)) << 4)] = v;
    v.x = pk_hi16(hi[1], hi[0]); v.y = pk_hi16(hi[3], hi[2]);
    *(uint2*)&ov[base + ((3 ^ (dq & 3)) << 4)] = v;
  }
}

// ---------------------------------------------------------------------------
// Main attention kernel.
// ---------------------------------------------------------------------------
__global__ __launch_bounds__(256, 2) void attn_mfma4(
    const float* __restrict__ x, const float* __restrict__ mask,
    const unsigned short* __restrict__ xbf,
    const unsigned short* __restrict__ xvt,
    float* __restrict__ out)
{
  const int tid = threadIdx.x;
  const int w = tid >> 6, l = tid & 63;
  const int l15 = l & 15, q4 = l >> 4;   // 16x16 roles
  const int l31 = l & 31, h2 = l >> 5;   // 32x32 roles

  // Pair-balanced LPT remap: fill-order slots c and c+32 get qq = 63-c and c,
  // so each CU's two resident blocks sum to 130 tiles.
  const int bid = (int)blockIdx.x;
  const int b = bid & 7;
  const int s = bid >> 3;
  const int qq = (s < 32) ? (63 - s) : (s - 32);
  const int i0 = qq << 5;                    // rows i0..i0+31

  const float* xb = x + (size_t)b * kT * kD;
  const float* mrow = mask + (size_t)b * kT;
  const unsigned short* xbfB = xbf + (size_t)b * kTilesPerBatch * kTileShorts;
  const unsigned short* xvtB = xvt + (size_t)b * kTilesPerBatch * kTileShorts;

  __shared__ unsigned short xKc[12288];      // chunk-major swizzled K tile
  __shared__ unsigned short VTb[12288];      // blocked-transposed V tile
  __shared__ float sPart[2][4][16][36];      // per-wave partial S (dbuf)
  __shared__ unsigned short Pm[2][32][16];   // masked P bf16, jstore (dbuf)
  __shared__ float corrS[2][32];
  __shared__ float invlS[32];
  __shared__ float msk[kT];                  // whole sit-mask row, f32

  // ---- issue mask-row preload (2 gload/wave, wave-own 2KB chunk) ----
  {
    const char* msrc = (const char*)mrow + 2048 * w;
    char* mdst = (char*)&msk[512 * w];
    gload_lds16(msrc + 16 * l, mdst);
    gload_lds16(msrc + 1024 + 16 * l, mdst + 1024);
  }

  // ---- Q fragments (bf16 direct from xbf): A[m=l15][k=8*q4+e] ----
  short8 qf[2][6];
#pragma unroll
  for (int mt = 0; mt < 2; ++mt) {
    const int tq = (i0 >> 4) + mt;
    const unsigned short* tp = xbfB + (size_t)tq * kTileShorts + w * 3072 + l15 * 192;
#pragma unroll
    for (int s6 = 0; s6 < 6; ++s6)
      qf[mt][s6] = *(const short8*)&tp[((4 * s6 + q4) ^ (l15 & 7)) << 3];
  }

  f32x16 o[6];
#pragma unroll
  for (int nt = 0; nt < 6; ++nt)
#pragma unroll
    for (int e = 0; e < 16; ++e) o[nt][e] = 0.0f;

  float mrun = -INFINITY, lrun = 0.0f;
  const float scale = 0.036084391824351615f;  // 1/sqrt(768)
  const int nTiles = i0 / 16 + 2;

  // softmax roles: 8 threads/row; jstore pair (2q,2q+1) <-> actual j {jA, jA+4}
  const int q = tid & 7, sr = tid >> 3;
  const int jA = (q >> 1) + 8 * (q & 1);
  const int irow = i0 + sr;

  // PV B-frag base offset into VTb (invariant over nt; +512 per nt)
  const int D0 = 48 * w + (l31 >> 2);
  const int vtb_off0 = D0 * 64 + (((l31 & 3) ^ (D0 & 3)) << 4)
                     + ((8 * h2) ^ (8 * ((l31 >> 4) & 1)));

  // stage helpers: each wave copies exactly the 6144B chunk it alone reads
  auto stageK = [&](int t) {
    const unsigned short* src = xbfB + (size_t)t * kTileShorts + w * 3072 + 8 * l;
    unsigned short* dst = &xKc[w * 3072];
#pragma unroll
    for (int i = 0; i < 6; ++i) gload_lds16(src + 512 * i, dst + 512 * i);
  };
  auto stageV = [&](int t) {
    const unsigned short* src = xvtB + (size_t)t * kTileShorts + w * 3072 + 8 * l;
    unsigned short* dst = &VTb[w * 3072];
#pragma unroll
    for (int i = 0; i < 6; ++i) gload_lds16(src + 512 * i, dst + 512 * i);
  };

  // ---- prologue: stage tile 0, drain everything except its 12 loads ----
  stageK(0);
  stageV(0);
  asm volatile("s_waitcnt vmcnt(12)" ::: "memory");  // msk + qf done
  lds_barrier();                                     // msk visible to all waves

  for (int t = 0; t < nTiles; ++t) {
    const int par = t & 1;
    const int j0 = t << 4;

    // own xK[t] chunk arrived (oldest 6 of 12 outstanding)
    asm volatile("s_waitcnt vmcnt(6)" ::: "memory");

    // ---- QK^T partial over this wave's 192-d chunk ----
    {
      f32x4 sf0, sf1;
#pragma unroll
      for (int e = 0; e < 4; ++e) { sf0[e] = 0.f; sf1[e] = 0.f; }
      const unsigned short* kbase = &xKc[w * 3072 + l15 * 192];
#pragma unroll
      for (int s6 = 0; s6 < 6; ++s6) {
        short8 kb = *(const short8*)&kbase[((4 * s6 + q4) ^ (l15 & 7)) << 3];
        sf0 = __builtin_amdgcn_mfma_f32_16x16x32_bf16(qf[0][s6], kb, sf0, 0, 0, 0);
        sf1 = __builtin_amdgcn_mfma_f32_16x16x32_bf16(qf[1][s6], kb, sf1, 0, 0, 0);
      }
      *(f32x4*)&sPart[par][w][l15][4 * q4]      = sf0;  // [w][j=l15][i-col]
      *(f32x4*)&sPart[par][w][l15][16 + 4 * q4] = sf1;
    }

    // issue next K tile into own chunk (ds_reads above complete first)
    if (t + 1 < nTiles) {
      asm volatile("s_waitcnt lgkmcnt(0)" ::: "memory");
      stageK(t + 1);
    }
    lds_barrier();  // B1: sPart[par] ready

    // ---- online softmax (8 thr/row; this thread: j = jA, jA+4) ----
    {
      float s0 = 0.f, s1 = 0.f;
#pragma unroll
      for (int ww = 0; ww < 4; ++ww) {
        s0 += sPart[par][ww][jA][sr];
        s1 += sPart[par][ww][jA + 4][sr];
      }
      const float mskA = msk[j0 + jA];
      const float mskB = msk[j0 + jA + 4];
      const int ja = j0 + jA, jb_ = j0 + jA + 4;
      float a0 = (ja  <= irow) ? s0 * scale : -INFINITY;
      float a1 = (jb_ <= irow) ? s1 * scale : -INFINITY;
      float loc = fmaxf(a0, a1);
      loc = fmaxf(loc, __shfl_xor(loc, 1, 64));
      loc = fmaxf(loc, __shfl_xor(loc, 2, 64));
      loc = fmaxf(loc, __shfl_xor(loc, 4, 64));
      const float mn = fmaxf(mrun, loc);
      const float corr = __expf(mrun - mn);   // tile 0: exp(-inf)=0
      const float p0 = __expf(a0 - mn);
      const float p1 = __expf(a1 - mn);
      float rs = p0 + p1;
      rs += __shfl_xor(rs, 1, 64);
      rs += __shfl_xor(rs, 2, 64);
      rs += __shfl_xor(rs, 4, 64);
      lrun = lrun * corr + rs;                // denominator: unmasked
      mrun = mn;
      const float w0 = (mskA != 0.f) ? p0 : 0.f;  // numerator: masked
      const float w1 = (mskB != 0.f) ? p1 : 0.f;
      *(unsigned*)&Pm[par][sr][2 * q] = pk_hi16(FB(w1), FB(w0));
      if (q == 0) corrS[par][sr] = corr;
    }
    lds_barrier();  // B2: Pm/corrS ready

    // own xvt[t] chunk arrived (xK[t+1] may stay in flight)
    if (t + 1 < nTiles) { asm volatile("s_waitcnt vmcnt(6)" ::: "memory"); }
    else                { asm volatile("s_waitcnt vmcnt(0)" ::: "memory"); }

    // ---- PV: O += P·V  (32x32x16, k in jstore order on both operands) ----
    {
      float cr[16];
#pragma unroll
      for (int e4 = 0; e4 < 4; ++e4) {
        f32x4 qd = *(const f32x4*)&corrS[par][8 * e4 + 4 * h2];
#pragma unroll
        for (int ee = 0; ee < 4; ++ee) cr[4 * e4 + ee] = qd[ee];
      }
#pragma unroll
      for (int nt = 0; nt < 6; ++nt)
#pragma unroll
        for (int e = 0; e < 16; ++e) o[nt][e] *= cr[e];
      short8 pa = *(const short8*)&Pm[par][l31][8 * h2];  // A[m=i][k=js]
#pragma unroll
      for (int nt = 0; nt < 6; ++nt) {
        short8 vb = *(const short8*)&VTb[vtb_off0 + 512 * nt];  // B[k=js][n=d]
        o[nt] = __builtin_amdgcn_mfma_f32_32x32x16_bf16(pa, vb, o[nt], 0, 0, 0);
      }
    }

    // issue next V tile into own chunk (vb ds_reads complete first)
    if (t + 1 < nTiles) {
      asm volatile("s_waitcnt lgkmcnt(0)" ::: "memory");
      stageV(t + 1);
    }
  }

  // ---- epilogue ----
  if (q == 0) invlS[sr] = (msk[irow] != 0.f) ? 1.0f / lrun : 0.0f;
  lds_barrier();
  {
    float il[16];
#pragma unroll
    for (int e4 = 0; e4 < 4; ++e4) {
      f32x4 qd = *(const f32x4*)&invlS[8 * e4 + 4 * h2];
#pragma unroll
      for (int ee = 0; ee < 4; ++ee) il[4 * e4 + ee] = qd[ee];
    }
    float* ob = out + (size_t)(b * kT + i0) * (2 * kD);
#pragma unroll
    for (int nt = 0; nt < 6; ++nt) {
      const int col = 192 * w + 32 * nt + l31;
#pragma unroll
      for (int e = 0; e < 16; ++e) {
        const int row = (e & 3) + 8 * (e >> 2) + 4 * h2;  // verified 32x32 C/D layout
        ob[(size_t)row * (2 * kD) + col] = o[nt][e] * il[e];
      }
    }
    // self-hidden half: exact fp32 copy
#pragma unroll
    for (int pass = 0; pass < 2; ++pass) {
      const int rr = (tid >> 4) + 16 * pass;
      const float* srcr = xb + (size_t)(i0 + rr) * kD;
      float* dstr = ob + (size_t)rr * (2 * kD) + kD;
#pragma unroll
      for (int it = 0; it < 12; ++it) {
        const int d4 = (tid & 15) + 16 * it;
        *(float4*)(dstr + 4 * d4) = *(const float4*)(srcr + 4 * d4);
      }
    }
  }
}

extern "C" void kernel_launch(void* const* d_in, const int* in_sizes, int n_in,
                              void* d_out, int out_size, void* d_ws, size_t ws_size,
                              hipStream_t stream) {
  const float* x    = (const float*)d_in[0];
  const float* mask = (const float*)d_in[1];
  float* out = (float*)d_out;
  unsigned short* xbf = (unsigned short*)d_ws;
  unsigned short* xvt = xbf + (size_t)8 * kTilesPerBatch * kTileShorts;
  // workspace use: 2 * 8 * 128 * 12288 * 2B = 50,331,648 B
  prep_bf16<<<dim3(8 * kTilesPerBatch), dim3(256), 0, stream>>>(x, xbf, xvt);
  attn_mfma4<<<dim3(512), dim3(256), 0, stream>>>(x, mask, xbf, xvt, out);
}

// Round 2
// 446.284 us; speedup vs baseline: 1.0905x; 1.0361x over previous
//
#include <hip/hip_runtime.h>
#include <math.h>

// B=8, T=2048, D=768. out[b,i,:768] = masked softmax attn (denominator over ALL
// causal j; sit-mask zeroes numerator only; row gated by mask_i), out[b,i,768:] = x[b,i].
//
// v5: split-K load balancing. Heavy Q-tiles (q>=32) split into two KV-halves
// (each <=64 tiles); halves write unnormalized partials (O,m,l); a combine
// kernel merges. 768 blocks > 512 resident slots -> hardware backfill keeps
// 2 blocks/CU until the tail. Blocks launched in global LPT (largest-first)
// order. Per-tile machinery identical to v4 (verified layouts untouched).
constexpr int kT = 2048;
constexpr int kD = 768;
constexpr int kTileShorts = 16 * kD;       // 12288 shorts per 16-row tile
constexpr int kTilesPerBatch = kT / 16;    // 128

typedef __attribute__((ext_vector_type(8))) short short8;
typedef __attribute__((ext_vector_type(4))) float f32x4;
typedef __attribute__((ext_vector_type(16))) float f32x16;

#define FB(f) __builtin_bit_cast(unsigned, (f))
__device__ __forceinline__ unsigned pk_hi16(unsigned hi, unsigned lo) {
  return __builtin_amdgcn_perm(hi, lo, 0x07060302);  // bf16 truncation pack
}
__device__ __forceinline__ unsigned pk_lo16(unsigned hi, unsigned lo) {
  return __builtin_amdgcn_perm(hi, lo, 0x05040100);
}

// Workgroup barrier WITHOUT the vmcnt(0) drain __syncthreads() emits.
__device__ __forceinline__ void lds_barrier() {
  asm volatile("" ::: "memory");
  __builtin_amdgcn_s_waitcnt(0xC07F);   // vmcnt=63, expcnt=7, lgkmcnt=0
  __builtin_amdgcn_s_barrier();
  asm volatile("" ::: "memory");
}

// Direct global->LDS copy, 16B/lane. LDS dest = wave-uniform base + lane*16.
__device__ __forceinline__ void gload_lds16(const void* g, void* l) {
  __builtin_amdgcn_global_load_lds(
      (const __attribute__((address_space(1))) unsigned int*)g,
      (__attribute__((address_space(3))) unsigned int*)l, 16, 0, 0);
}

// ---------------------------------------------------------------------------
// Prep: x f32 -> bf16 workspace, both layouts (unchanged from v4).
// ---------------------------------------------------------------------------
__global__ __launch_bounds__(256) void prep_bf16(
    const float* __restrict__ x,
    unsigned short* __restrict__ xbf, unsigned short* __restrict__ xvt)
{
  const int tid = threadIdx.x;
  const int w = tid >> 6, l = tid & 63;
  const int l15 = l & 15, q4 = l >> 4;
  const int bt = (int)blockIdx.x;            // b*128 + t
  const float* xb = x + (size_t)bt * 16 * kD;
  unsigned short* ob = xbf + (size_t)bt * kTileShorts;
  unsigned short* ov = xvt + (size_t)bt * kTileShorts;

#pragma unroll
  for (int it = 0; it < 3; ++it) {
    const int dq = l15 + 16 * it + 48 * w;   // global d-quad index, [0,192)
    unsigned lo[4], hi[4];
#pragma unroll
    for (int jj = 0; jj < 4; ++jj) {
      const float4 f = *(const float4*)(xb + (size_t)(q4 + 4 * jj) * kD + 4 * dq);
      lo[jj] = pk_hi16(FB(f.y), FB(f.x));    // bf16 d+1 | d+0
      hi[jj] = pk_hi16(FB(f.w), FB(f.z));    // bf16 d+3 | d+2
    }
    // ---- xbf: chunked row-major + 16B-group XOR swizzle ----
    const int dp = 4 * (l15 + 16 * it);      // d' within w-chunk, [0,192)
    const int g = dp >> 3, e0 = dp & 7;      // e0 in {0,4}
#pragma unroll
    for (int jj = 0; jj < 4; ++jj) {
      const int j = q4 + 4 * jj;
      uint2 v; v.x = lo[jj]; v.y = hi[jj];
      *(uint2*)&ob[w * 3072 + j * 192 + ((g ^ (j & 7)) << 3) + e0] = v;
    }
    // ---- xvt: VTb blocked transpose ----
    const int jb = (4 * q4) ^ (8 * ((dq >> 2) & 1));
    const int base = dq * 64 + jb;
    uint2 v;
    v.x = pk_lo16(lo[1], lo[0]); v.y = pk_lo16(lo[3], lo[2]);
    *(uint2*)&ov[base + ((0 ^ (dq & 3)) << 4)] = v;
    v.x = pk_hi16(lo[1], lo[0]); v.y = pk_hi16(lo[3], lo[2]);
    *(uint2*)&ov[base + ((1 ^ (dq & 3)) << 4)] = v;
    v.x = pk_lo16(hi[1], hi[0]); v.y = pk_lo16(hi[3], hi[2]);
    *(uint2*)&ov[base + ((2 ^ (dq & 3)) << 4)] = v;
    v.x = pk_hi16(hi[1], hi[0]); v.y = pk_hi16(hi[3], hi[2]);
    *(uint2*)&ov[base + ((3 ^ (dq & 3)) << 4)] = v;
  }
}

// ---------------------------------------------------------------------------
// Main attention kernel (split-K aware).
//   mode 0: light Q-tile (q<32), full KV range, direct final write.
//   mode 1: heavy half-1, writes raw partial O to out[..,0:768] + (m,l) to ml.
//   mode 2: heavy half-2, writes raw partial O to out[..,768:1536] + (m,l).
// ---------------------------------------------------------------------------
__global__ __launch_bounds__(256, 2) void attn_mfma5(
    const float* __restrict__ x, const float* __restrict__ mask,
    const unsigned short* __restrict__ xbf,
    const unsigned short* __restrict__ xvt,
    float* __restrict__ out, float* __restrict__ ml)
{
  const int tid = threadIdx.x;
  const int w = tid >> 6, l = tid & 63;
  const int l15 = l & 15, q4 = l >> 4;   // 16x16 roles
  const int l31 = l & 31, h2 = l >> 5;   // 32x32 roles

  // ---- global LPT block mapping: 96 slots/batch, largest work first ----
  // Band s<80: group g (size 64-g): 2 heavy halves of q=63-g, plus (g even)
  // one light ql=31-g/2. cum(g) = 2g + ceil(g/2). Band s>=80: lights 15..0.
  const int bid = (int)blockIdx.x;
  const int b = bid & 7;
  const int s = bid >> 3;                    // 0..95
  int qq, t0, t1, mode;
  if (s < 80) {
    int g = (s * 2) / 5;
    if (g > 31) g = 31;
    while (g < 31 && (2 * (g + 1) + ((g + 2) >> 1)) <= s) ++g;
    while (g > 0 && (2 * g + ((g + 1) >> 1)) > s) --g;
    const int r = s - (2 * g + ((g + 1) >> 1));
    if (r < 2) {                             // heavy half
      qq = 63 - g;                           // 32..63
      const int H = qq + 1;                  // tiles per half
      mode = 1 + r;
      t0 = (r == 0) ? 0 : H;
      t1 = (r == 0) ? H : 2 * H;
    } else {                                 // in-band light
      qq = 31 - (g >> 1);                    // 31..16
      mode = 0; t0 = 0; t1 = 2 * qq + 2;
    }
  } else {                                   // tail lights
    qq = 15 - (s - 80);                      // 15..0
    mode = 0; t0 = 0; t1 = 2 * qq + 2;
  }
  const int i0 = qq << 5;                    // rows i0..i0+31

  const float* xb = x + (size_t)b * kT * kD;
  const float* mrow = mask + (size_t)b * kT;
  const unsigned short* xbfB = xbf + (size_t)b * kTilesPerBatch * kTileShorts;
  const unsigned short* xvtB = xvt + (size_t)b * kTilesPerBatch * kTileShorts;

  __shared__ unsigned short xKc[12288];      // chunk-major swizzled K tile
  __shared__ unsigned short VTb[12288];      // blocked-transposed V tile
  __shared__ float sPart[2][4][16][36];      // per-wave partial S (dbuf)
  __shared__ unsigned short Pm[2][32][16];   // masked P bf16, jstore (dbuf)
  __shared__ float corrS[2][32];
  __shared__ float invlS[32];
  __shared__ float msk[kT];                  // whole sit-mask row, f32

  // ---- issue mask-row preload (2 gload/wave, wave-own 2KB chunk) ----
  {
    const char* msrc = (const char*)mrow + 2048 * w;
    char* mdst = (char*)&msk[512 * w];
    gload_lds16(msrc + 16 * l, mdst);
    gload_lds16(msrc + 1024 + 16 * l, mdst + 1024);
  }

  // ---- Q fragments (bf16 direct from xbf): A[m=l15][k=8*q4+e] ----
  short8 qf[2][6];
#pragma unroll
  for (int mt = 0; mt < 2; ++mt) {
    const int tq = (i0 >> 4) + mt;
    const unsigned short* tp = xbfB + (size_t)tq * kTileShorts + w * 3072 + l15 * 192;
#pragma unroll
    for (int s6 = 0; s6 < 6; ++s6)
      qf[mt][s6] = *(const short8*)&tp[((4 * s6 + q4) ^ (l15 & 7)) << 3];
  }

  f32x16 o[6];
#pragma unroll
  for (int nt = 0; nt < 6; ++nt)
#pragma unroll
    for (int e = 0; e < 16; ++e) o[nt][e] = 0.0f;

  float mrun = -INFINITY, lrun = 0.0f;
  const float scale = 0.036084391824351615f;  // 1/sqrt(768)

  // softmax roles: 8 threads/row; jstore pair (2q,2q+1) <-> actual j {jA, jA+4}
  const int q = tid & 7, sr = tid >> 3;
  const int jA = (q >> 1) + 8 * (q & 1);
  const int irow = i0 + sr;

  // PV B-frag base offset into VTb (invariant over nt; +512 per nt)
  const int D0 = 48 * w + (l31 >> 2);
  const int vtb_off0 = D0 * 64 + (((l31 & 3) ^ (D0 & 3)) << 4)
                     + ((8 * h2) ^ (8 * ((l31 >> 4) & 1)));

  // stage helpers: each wave copies exactly the 6144B chunk it alone reads
  auto stageK = [&](int t) {
    const unsigned short* src = xbfB + (size_t)t * kTileShorts + w * 3072 + 8 * l;
    unsigned short* dst = &xKc[w * 3072];
#pragma unroll
    for (int i = 0; i < 6; ++i) gload_lds16(src + 512 * i, dst + 512 * i);
  };
  auto stageV = [&](int t) {
    const unsigned short* src = xvtB + (size_t)t * kTileShorts + w * 3072 + 8 * l;
    unsigned short* dst = &VTb[w * 3072];
#pragma unroll
    for (int i = 0; i < 6; ++i) gload_lds16(src + 512 * i, dst + 512 * i);
  };

  // ---- prologue: stage first tile, drain everything except its 12 loads ----
  stageK(t0);
  stageV(t0);
  asm volatile("s_waitcnt vmcnt(12)" ::: "memory");  // msk + qf done
  lds_barrier();                                     // msk visible to all waves

  for (int t = t0; t < t1; ++t) {
    const int par = t & 1;
    const int j0 = t << 4;

    // own xK[t] chunk arrived (oldest 6 of 12 outstanding)
    asm volatile("s_waitcnt vmcnt(6)" ::: "memory");

    // ---- QK^T partial over this wave's 192-d chunk ----
    {
      f32x4 sf0, sf1;
#pragma unroll
      for (int e = 0; e < 4; ++e) { sf0[e] = 0.f; sf1[e] = 0.f; }
      const unsigned short* kbase = &xKc[w * 3072 + l15 * 192];
#pragma unroll
      for (int s6 = 0; s6 < 6; ++s6) {
        short8 kb = *(const short8*)&kbase[((4 * s6 + q4) ^ (l15 & 7)) << 3];
        sf0 = __builtin_amdgcn_mfma_f32_16x16x32_bf16(qf[0][s6], kb, sf0, 0, 0, 0);
        sf1 = __builtin_amdgcn_mfma_f32_16x16x32_bf16(qf[1][s6], kb, sf1, 0, 0, 0);
      }
      *(f32x4*)&sPart[par][w][l15][4 * q4]      = sf0;  // [w][j=l15][i-col]
      *(f32x4*)&sPart[par][w][l15][16 + 4 * q4] = sf1;
    }

    // issue next K tile into own chunk (ds_reads above complete first)
    if (t + 1 < t1) {
      asm volatile("s_waitcnt lgkmcnt(0)" ::: "memory");
      stageK(t + 1);
    }
    lds_barrier();  // B1: sPart[par] ready

    // ---- online softmax (8 thr/row; this thread: j = jA, jA+4) ----
    {
      float s0 = 0.f, s1 = 0.f;
#pragma unroll
      for (int ww = 0; ww < 4; ++ww) {
        s0 += sPart[par][ww][jA][sr];
        s1 += sPart[par][ww][jA + 4][sr];
      }
      const float mskA = msk[j0 + jA];
      const float mskB = msk[j0 + jA + 4];
      const int ja = j0 + jA, jb_ = j0 + jA + 4;
      float a0 = (ja  <= irow) ? s0 * scale : -INFINITY;
      float a1 = (jb_ <= irow) ? s1 * scale : -INFINITY;
      float loc = fmaxf(a0, a1);
      loc = fmaxf(loc, __shfl_xor(loc, 1, 64));
      loc = fmaxf(loc, __shfl_xor(loc, 2, 64));
      loc = fmaxf(loc, __shfl_xor(loc, 4, 64));
      const float mn = fmaxf(mrun, loc);
      const float corr = __expf(mrun - mn);   // first tile: exp(-inf)=0
      const float p0 = __expf(a0 - mn);
      const float p1 = __expf(a1 - mn);
      float rs = p0 + p1;
      rs += __shfl_xor(rs, 1, 64);
      rs += __shfl_xor(rs, 2, 64);
      rs += __shfl_xor(rs, 4, 64);
      lrun = lrun * corr + rs;                // denominator: unmasked
      mrun = mn;
      const float w0 = (mskA != 0.f) ? p0 : 0.f;  // numerator: masked
      const float w1 = (mskB != 0.f) ? p1 : 0.f;
      *(unsigned*)&Pm[par][sr][2 * q] = pk_hi16(FB(w1), FB(w0));
      if (q == 0) corrS[par][sr] = corr;
    }
    lds_barrier();  // B2: Pm/corrS ready

    // own xvt[t] chunk arrived (xK[t+1] may stay in flight)
    if (t + 1 < t1) { asm volatile("s_waitcnt vmcnt(6)" ::: "memory"); }
    else            { asm volatile("s_waitcnt vmcnt(0)" ::: "memory"); }

    // ---- PV: O += P·V  (32x32x16, k in jstore order on both operands) ----
    {
      float cr[16];
#pragma unroll
      for (int e4 = 0; e4 < 4; ++e4) {
        f32x4 qd = *(const f32x4*)&corrS[par][8 * e4 + 4 * h2];
#pragma unroll
        for (int ee = 0; ee < 4; ++ee) cr[4 * e4 + ee] = qd[ee];
      }
#pragma unroll
      for (int nt = 0; nt < 6; ++nt)
#pragma unroll
        for (int e = 0; e < 16; ++e) o[nt][e] *= cr[e];
      short8 pa = *(const short8*)&Pm[par][l31][8 * h2];  // A[m=i][k=js]
#pragma unroll
      for (int nt = 0; nt < 6; ++nt) {
        short8 vb = *(const short8*)&VTb[vtb_off0 + 512 * nt];  // B[k=js][n=d]
        o[nt] = __builtin_amdgcn_mfma_f32_32x32x16_bf16(pa, vb, o[nt], 0, 0, 0);
      }
    }

    // issue next V tile into own chunk (vb ds_reads complete first)
    if (t + 1 < t1) {
      asm volatile("s_waitcnt lgkmcnt(0)" ::: "memory");
      stageV(t + 1);
    }
  }

  // ---- epilogue ----
  if (mode == 0) {
    if (q == 0) invlS[sr] = (msk[irow] != 0.f) ? 1.0f / lrun : 0.0f;
    lds_barrier();
    float il[16];
#pragma unroll
    for (int e4 = 0; e4 < 4; ++e4) {
      f32x4 qd = *(const f32x4*)&invlS[8 * e4 + 4 * h2];
#pragma unroll
      for (int ee = 0; ee < 4; ++ee) il[4 * e4 + ee] = qd[ee];
    }
    float* ob = out + (size_t)(b * kT + i0) * (2 * kD);
#pragma unroll
    for (int nt = 0; nt < 6; ++nt) {
      const int col = 192 * w + 32 * nt + l31;
#pragma unroll
      for (int e = 0; e < 16; ++e) {
        const int row = (e & 3) + 8 * (e >> 2) + 4 * h2;  // verified 32x32 C/D layout
        ob[(size_t)row * (2 * kD) + col] = o[nt][e] * il[e];
      }
    }
    // self-hidden half: exact fp32 copy
#pragma unroll
    for (int pass = 0; pass < 2; ++pass) {
      const int rr = (tid >> 4) + 16 * pass;
      const float* srcr = xb + (size_t)(i0 + rr) * kD;
      float* dstr = ob + (size_t)rr * (2 * kD) + kD;
#pragma unroll
      for (int it = 0; it < 12; ++it) {
        const int d4 = (tid & 15) + 16 * it;
        *(float4*)(dstr + 4 * d4) = *(const float4*)(srcr + 4 * d4);
      }
    }
  } else {
    // heavy half: write raw partial O (no normalization, no row gate)
    float* ob = out + (size_t)(b * kT + i0) * (2 * kD) + ((mode == 2) ? kD : 0);
#pragma unroll
    for (int nt = 0; nt < 6; ++nt) {
      const int col = 192 * w + 32 * nt + l31;
#pragma unroll
      for (int e = 0; e < 16; ++e) {
        const int row = (e & 3) + 8 * (e >> 2) + 4 * h2;
        ob[(size_t)row * (2 * kD) + col] = o[nt][e];
      }
    }
    if (q == 0) {
      const int base = (((b * 32 + (qq - 32)) * 2 + (mode - 1)) * 64);
      ml[base + sr]      = mrun;
      ml[base + 32 + sr] = lrun;
    }
  }
}

// ---------------------------------------------------------------------------
// Combine: merge the two halves of heavy Q-tiles and restore the self-copy.
// grid = 8 batches x 32 heavy tiles; 256 threads (192 active per row pass).
// ---------------------------------------------------------------------------
__global__ __launch_bounds__(256) void combine_heavy(
    const float* __restrict__ x, const float* __restrict__ mask,
    const float* __restrict__ ml, float* __restrict__ out)
{
  const int tid = threadIdx.x;
  const int bid = (int)blockIdx.x;     // b*32 + hq
  const int b = bid & 7;
  const int hq = bid >> 3;             // 0..31 -> q = hq+32
  const int i0 = (hq + 32) << 5;
  const float* mrow = mask + (size_t)b * kT;
  const float* mlq = ml + (((size_t)b * 32 + hq) * 2) * 64;

  for (int r = 0; r < 32; ++r) {
    const int i = i0 + r;
    float* orow = out + (size_t)(b * kT + i) * (2 * kD);
    const float* xrow = x + (size_t)(b * kT + i) * kD;
    const float m1 = mlq[r],      l1 = mlq[32 + r];
    const float m2 = mlq[64 + r], l2 = mlq[96 + r];
    const float m = fmaxf(m1, m2);
    const float al = __expf(m1 - m), be = __expf(m2 - m);
    const float lsum = al * l1 + be * l2;
    const float gate = (mrow[i] != 0.f) ? 1.0f / lsum : 0.0f;
    const float ga = gate * al, gb = gate * be;
    if (tid < 192) {
      float4 o1 = *(const float4*)(orow + 4 * tid);
      float4 o2 = *(const float4*)(orow + kD + 4 * tid);
      float4 xv = *(const float4*)(xrow + 4 * tid);
      float4 fo;
      fo.x = ga * o1.x + gb * o2.x;
      fo.y = ga * o1.y + gb * o2.y;
      fo.z = ga * o1.z + gb * o2.z;
      fo.w = ga * o1.w + gb * o2.w;
      *(float4*)(orow + 4 * tid) = fo;          // final attn half
      *(float4*)(orow + kD + 4 * tid) = xv;     // restore self-copy
    }
  }
}

extern "C" void kernel_launch(void* const* d_in, const int* in_sizes, int n_in,
                              void* d_out, int out_size, void* d_ws, size_t ws_size,
                              hipStream_t stream) {
  const float* x    = (const float*)d_in[0];
  const float* mask = (const float*)d_in[1];
  float* out = (float*)d_out;
  unsigned short* xbf = (unsigned short*)d_ws;
  unsigned short* xvt = xbf + (size_t)8 * kTilesPerBatch * kTileShorts;
  float* ml = (float*)(xvt + (size_t)8 * kTilesPerBatch * kTileShorts);
  // workspace use: 2 * 8 * 128 * 12288 * 2B + 8*32*2*64*4B = 50,462,720 B
  prep_bf16<<<dim3(8 * kTilesPerBatch), dim3(256), 0, stream>>>(x, xbf, xvt);
  attn_mfma5<<<dim3(768), dim3(256), 0, stream>>>(x, mask, xbf, xvt, out, ml);
  combine_heavy<<<dim3(256), dim3(256), 0, stream>>>(x, mask, ml, out);
}